// Round 4
// baseline (2049.451 us; speedup 1.0000x reference)
//
#include <hip/hip_runtime.h>
#include <math.h>

#define NUSERS 100000
#define NITEMS 50000
#define BATCH  64
#define ORDER  8
#define SCAN_BLOCKS 256
#define BUCK_SHIFT 7                              // 128 rows per bucket
#define NUBUCK ((NUSERS + 127) >> BUCK_SHIFT)     // 782
#define NIBUCK ((NITEMS + 127) >> BUCK_SHIFT)     // 391

// Packed edge: gather index + value, one 8B unit
struct __align__(8) Edge { int idx; float val; };
// Staging record: ((key & 127) << 17) | idx  (idx < 131072), + value. 8B.
struct __align__(8) SRec { int packed; float val; };

// ---------------------------------------------------------------------------
// 32x32 LDS-tiled transpose: in[R][C] -> out[C][R]
// ---------------------------------------------------------------------------
__global__ void transpose_k(const float* __restrict__ in, float* __restrict__ out,
                            int R, int C) {
    __shared__ float tile[32][33];
    const int cb = blockIdx.x * 32;
    const int rb = blockIdx.y * 32;
    for (int i = threadIdx.y; i < 32; i += 8) {
        int r = rb + i, c = cb + threadIdx.x;
        if (r < R && c < C) tile[i][threadIdx.x] = in[(size_t)r * C + c];
    }
    __syncthreads();
    for (int i = threadIdx.y; i < 32; i += 8) {
        int c = cb + i, r = rb + threadIdx.x;
        if (c < C && r < R) out[(size_t)c * R + r] = tile[threadIdx.x][i];
    }
}

// ---------------------------------------------------------------------------
// CSR construction
// ---------------------------------------------------------------------------
__global__ void hist_k(const int* __restrict__ row, const int* __restrict__ col,
                       int* __restrict__ udeg, int* __restrict__ ideg, int nnz) {
    int i = blockIdx.x * blockDim.x + threadIdx.x;
    if (i < nnz) {
        atomicAdd(&udeg[row[i]], 1);
        atomicAdd(&ideg[col[i]], 1);
    }
}

__global__ void scan_partial(const int* __restrict__ deg, int* __restrict__ bsum, int n) {
    __shared__ int ls[256];
    const int chunk = (n + SCAN_BLOCKS - 1) / SCAN_BLOCKS;
    const int b0 = blockIdx.x * chunk;
    const int e0 = min(b0 + chunk, n);
    int s = 0;
    for (int i = b0 + threadIdx.x; i < e0; i += 256) s += deg[i];
    ls[threadIdx.x] = s;
    __syncthreads();
    for (int off = 128; off > 0; off >>= 1) {
        if (threadIdx.x < off) ls[threadIdx.x] += ls[threadIdx.x + off];
        __syncthreads();
    }
    if (threadIdx.x == 0) bsum[blockIdx.x] = ls[0];
}

__global__ void scan_bsum(const int* __restrict__ bsum, int* __restrict__ bofs) {
    __shared__ int ls[SCAN_BLOCKS];
    const int t = threadIdx.x;
    int v = bsum[t];
    ls[t] = v;
    __syncthreads();
    for (int off = 1; off < SCAN_BLOCKS; off <<= 1) {
        int u = (t >= off) ? ls[t - off] : 0;
        __syncthreads();
        ls[t] += u;
        __syncthreads();
    }
    bofs[t] = ls[t] - v;
}

__global__ void scan_final(const int* __restrict__ deg, const int* __restrict__ bofs,
                           int* __restrict__ ptr, int* __restrict__ cur, int n) {
    __shared__ int ls[256];
    const int chunk = (n + SCAN_BLOCKS - 1) / SCAN_BLOCKS;
    const int b0 = blockIdx.x * chunk;
    const int e0 = min(b0 + chunk, n);
    int carry = bofs[blockIdx.x];
    for (int base = b0; base < e0; base += 256) {
        int i = base + threadIdx.x;
        int v = (i < e0) ? deg[i] : 0;
        ls[threadIdx.x] = v;
        __syncthreads();
        for (int off = 1; off < 256; off <<= 1) {
            int u = (threadIdx.x >= off) ? ls[threadIdx.x - off] : 0;
            __syncthreads();
            ls[threadIdx.x] += u;
            __syncthreads();
        }
        if (i < e0) {
            int excl = carry + ls[threadIdx.x] - v;
            ptr[i] = excl;
            cur[i] = excl;
        }
        int tilesum = ls[255];
        __syncthreads();
        carry += tilesum;
    }
    if (blockIdx.x == SCAN_BLOCKS - 1 && threadIdx.x == 0)
        ptr[n] = carry;
}

// bcur[b] = ptr[b*128] for both directions
__global__ void init_bcur(const int* __restrict__ uptr, const int* __restrict__ iptr,
                          int* __restrict__ bcurU, int* __restrict__ bcurI) {
    int t = blockIdx.x * blockDim.x + threadIdx.x;
    if (t < NUBUCK) bcurU[t] = uptr[t << BUCK_SHIFT];
    if (t < NIBUCK) bcurI[t] = iptr[t << BUCK_SHIFT];
}

// Pass A: scatter packed records into bucket-contiguous staging.
// Hot write set = bucket tails (~150 KB), L2-resident.
__global__ void bucket_scatter(const int* __restrict__ row, const int* __restrict__ col,
                               const float* __restrict__ vals,
                               int* __restrict__ bcurU, SRec* __restrict__ stU,
                               int* __restrict__ bcurI, SRec* __restrict__ stI,
                               int nnz) {
    int i = blockIdx.x * blockDim.x + threadIdx.x;
    if (i < nnz) {
        int r = row[i], c = col[i];
        float v = vals[i];
        int pu = atomicAdd(&bcurU[r >> BUCK_SHIFT], 1);
        stU[pu] = SRec{((r & 127) << 17) | c, v};
        int pi = atomicAdd(&bcurI[c >> BUCK_SHIFT], 1);
        stI[pi] = SRec{((c & 127) << 17) | r, v};
    }
}

// Pass B: one block per bucket; streaming read of staging slice, scatter into
// the bucket's final CSR window (~16-32 KB, L2-hot -> no writeback amp).
__global__ void bucket_fill(const int* __restrict__ ptr, const SRec* __restrict__ st,
                            int* __restrict__ cur, Edge* __restrict__ edge, int nrows) {
    const int b = blockIdx.x;
    const int rbase = b << BUCK_SHIFT;
    const int lo = ptr[rbase];
    const int hi = ptr[min(rbase + 128, nrows)];
    for (int j = lo + threadIdx.x; j < hi; j += blockDim.x) {
        SRec s = st[j];
        int key = rbase + (s.packed >> 17);
        int p = atomicAdd(&cur[key], 1);
        edge[p] = Edge{s.packed & 0x1FFFF, s.val};
    }
}

// ---------------------------------------------------------------------------
// Gather SpMM: one wave per output row, lane = batch element.
// ---------------------------------------------------------------------------
__global__ void spmm_csr(const int* __restrict__ ptr, const Edge* __restrict__ ed,
                         const float* __restrict__ x, float* __restrict__ y, int nrows) {
    const int lane = threadIdx.x & 63;
    const int r = (blockIdx.x * blockDim.x + threadIdx.x) >> 6;
    if (r >= nrows) return;
    const int b = ptr[r], e = ptr[r + 1];
    float a0 = 0.f, a1 = 0.f, a2 = 0.f, a3 = 0.f;
    int j = b;
    for (; j + 3 < e; j += 4) {
        Edge e0 = ed[j], e1 = ed[j + 1], e2 = ed[j + 2], e3 = ed[j + 3];
        a0 += e0.val * x[(size_t)e0.idx * BATCH + lane];
        a1 += e1.val * x[(size_t)e1.idx * BATCH + lane];
        a2 += e2.val * x[(size_t)e2.idx * BATCH + lane];
        a3 += e3.val * x[(size_t)e3.idx * BATCH + lane];
    }
    for (; j < e; ++j) { Edge eo = ed[j]; a0 += eo.val * x[(size_t)eo.idx * BATCH + lane]; }
    y[(size_t)r * BATCH + lane] = (a0 + a1) + (a2 + a3);
}

__global__ void spmm2_first(const int* __restrict__ ptr, const Edge* __restrict__ ed,
                            const float* __restrict__ y, const float* __restrict__ s,
                            float* __restrict__ t1, float* __restrict__ out,
                            float c0, float c1, int nrows) {
    const int lane = threadIdx.x & 63;
    const int r = (blockIdx.x * blockDim.x + threadIdx.x) >> 6;
    if (r >= nrows) return;
    const int b = ptr[r], e = ptr[r + 1];
    float a0 = 0.f, a1 = 0.f, a2 = 0.f, a3 = 0.f;
    int j = b;
    for (; j + 3 < e; j += 4) {
        Edge e0 = ed[j], e1 = ed[j + 1], e2 = ed[j + 2], e3 = ed[j + 3];
        a0 += e0.val * y[(size_t)e0.idx * BATCH + lane];
        a1 += e1.val * y[(size_t)e1.idx * BATCH + lane];
        a2 += e2.val * y[(size_t)e2.idx * BATCH + lane];
        a3 += e3.val * y[(size_t)e3.idx * BATCH + lane];
    }
    for (; j < e; ++j) { Edge eo = ed[j]; a0 += eo.val * y[(size_t)eo.idx * BATCH + lane]; }
    float z = (a0 + a1) + (a2 + a3);
    size_t i = (size_t)r * BATCH + lane;
    float sv = s[i];
    float t = sv - 2.0f * z;
    t1[i] = t;
    out[i] = c0 * sv + c1 * t;
}

__global__ void spmm2_k(const int* __restrict__ ptr, const Edge* __restrict__ ed,
                        const float* __restrict__ y, const float* __restrict__ t1,
                        float* __restrict__ t0t2, float* __restrict__ out,
                        float ck, int nrows) {
    const int lane = threadIdx.x & 63;
    const int r = (blockIdx.x * blockDim.x + threadIdx.x) >> 6;
    if (r >= nrows) return;
    const int b = ptr[r], e = ptr[r + 1];
    float a0 = 0.f, a1 = 0.f, a2 = 0.f, a3 = 0.f;
    int j = b;
    for (; j + 3 < e; j += 4) {
        Edge e0 = ed[j], e1 = ed[j + 1], e2 = ed[j + 2], e3 = ed[j + 3];
        a0 += e0.val * y[(size_t)e0.idx * BATCH + lane];
        a1 += e1.val * y[(size_t)e1.idx * BATCH + lane];
        a2 += e2.val * y[(size_t)e2.idx * BATCH + lane];
        a3 += e3.val * y[(size_t)e3.idx * BATCH + lane];
    }
    for (; j < e; ++j) { Edge eo = ed[j]; a0 += eo.val * y[(size_t)eo.idx * BATCH + lane]; }
    float z = (a0 + a1) + (a2 + a3);
    size_t i = (size_t)r * BATCH + lane;
    float t2 = 2.0f * t1[i] - 4.0f * z - t0t2[i];
    t0t2[i] = t2;
    out[i] += ck * t2;
}

// ---------------------------------------------------------------------------
// Host-side exact replica of reference cheby_coeffs
// ---------------------------------------------------------------------------
static void cheby_coeffs_host(float* c) {
    const int order = ORDER, flatness = 2;
    const double PI = 3.14159265358979323846;
    double tgt[ORDER + 1], nodes[ORDER + 1];
    for (int x = 0; x <= order; ++x) {
        double xv = cos((double)(order - x) / order * PI);
        xv = nearbyint(xv * 1000.0) / 1000.0;
        double t = (xv < 0.0) ? pow(-xv, (double)flatness) * 0.5 + 0.5
                              : pow(xv, (double)flatness) * (-0.5) + 0.5;
        tgt[x] = nearbyint(t * 1000.0) / 1000.0;
    }
    for (int k = 1; k <= order + 1; ++k)
        nodes[k - 1] = cos((order + 1 + 0.5 - k) / (double)(order + 1) * PI);

    double prev[ORDER + 1], cur[ORDER + 1], nxt[ORDER + 1];
    double sums[ORDER + 1];
    double s0 = 0, s1 = 0;
    for (int i = 0; i <= order; ++i) {
        prev[i] = tgt[i];
        cur[i]  = nodes[i] * tgt[i];
        s0 += prev[i];
        s1 += cur[i];
    }
    sums[0] = s0; sums[1] = s1;
    for (int j = 2; j <= order; ++j) {
        double s = 0;
        for (int i = 0; i <= order; ++i) {
            nxt[i] = nodes[i] * cur[i] * 2.0 - prev[i];
            s += nxt[i];
        }
        sums[j] = s;
        for (int i = 0; i <= order; ++i) { prev[i] = cur[i]; cur[i] = nxt[i]; }
    }
    for (int j = 0; j <= order; ++j)
        c[j] = (float)(sums[j] * (2.0 / (order + 1)));
    c[0] *= 0.5f;
}

extern "C" void kernel_launch(void* const* d_in, const int* in_sizes, int n_in,
                              void* d_out, int out_size, void* d_ws, size_t ws_size,
                              hipStream_t stream) {
    const float* signal = (const float*)d_in[0];   // [BATCH, NITEMS]
    const float* vals   = (const float*)d_in[1];   // [NNZ]
    const int*   row    = (const int*)d_in[2];     // [NNZ] -> users
    const int*   col    = (const int*)d_in[3];     // [NNZ] -> items
    const int nnz = in_sizes[1];

    char* wsb = (char*)d_ws;
    size_t off = 0;
    auto carve = [&](size_t nbytes) {
        void* p = wsb + off;
        off += (nbytes + 15) & ~(size_t)15;
        return p;
    };
    const size_t NB = (size_t)NITEMS * BATCH;
    const size_t UB = (size_t)NUSERS * BATCH;
    float* bufA = (float*)carve(NB * 4);
    float* bufB = (float*)carve(NB * 4);
    float* obuf = (float*)carve(NB * 4);
    float* ybuf = (float*)carve(UB * 4);
    int*   udeg = (int*)carve(NUSERS * 4);
    int*   ideg = (int*)carve(NITEMS * 4);
    int*   uptr = (int*)carve((NUSERS + 1) * 4);
    int*   ucur = (int*)carve(NUSERS * 4);
    int*   iptr = (int*)carve((NITEMS + 1) * 4);
    int*   icur = (int*)carve(NITEMS * 4);
    int*   bsum = (int*)carve(SCAN_BLOCKS * 4);
    int*   bofs = (int*)carve(SCAN_BLOCKS * 4);
    int*   bcurU = (int*)carve(NUBUCK * 4);
    int*   bcurI = (int*)carve(NIBUCK * 4);
    SRec*  stU  = (SRec*)carve((size_t)nnz * 8);
    SRec*  stI  = (SRec*)carve((size_t)nnz * 8);
    Edge*  uedge = (Edge*)carve((size_t)nnz * 8);
    Edge*  iedge = (Edge*)carve((size_t)nnz * 8);
    (void)ws_size;

    float c[ORDER + 1];
    cheby_coeffs_host(c);

    // ---- CSR build ----
    hipMemsetAsync(udeg, 0, (size_t)(NUSERS + NITEMS) * 4, stream);  // udeg+ideg adjacent
    hist_k<<<(nnz + 255) / 256, 256, 0, stream>>>(row, col, udeg, ideg, nnz);

    scan_partial<<<SCAN_BLOCKS, 256, 0, stream>>>(udeg, bsum, NUSERS);
    scan_bsum<<<1, SCAN_BLOCKS, 0, stream>>>(bsum, bofs);
    scan_final<<<SCAN_BLOCKS, 256, 0, stream>>>(udeg, bofs, uptr, ucur, NUSERS);

    scan_partial<<<SCAN_BLOCKS, 256, 0, stream>>>(ideg, bsum, NITEMS);
    scan_bsum<<<1, SCAN_BLOCKS, 0, stream>>>(bsum, bofs);
    scan_final<<<SCAN_BLOCKS, 256, 0, stream>>>(ideg, bofs, iptr, icur, NITEMS);

    init_bcur<<<(max(NUBUCK, NIBUCK) + 255) / 256, 256, 0, stream>>>(uptr, iptr, bcurU, bcurI);
    bucket_scatter<<<(nnz + 255) / 256, 256, 0, stream>>>(row, col, vals,
                                                          bcurU, stU, bcurI, stI, nnz);
    bucket_fill<<<NUBUCK, 256, 0, stream>>>(uptr, stU, ucur, uedge, NUSERS);
    bucket_fill<<<NIBUCK, 256, 0, stream>>>(iptr, stI, icur, iedge, NITEMS);

    // ---- s = signal^T ----
    dim3 tb(32, 8);
    transpose_k<<<dim3((NITEMS + 31) / 32, (BATCH + 31) / 32), tb, 0, stream>>>(
        signal, bufA, BATCH, NITEMS);

    const int ug = (NUSERS * 64 + 255) / 256;
    const int ig = (NITEMS * 64 + 255) / 256;

    // ---- k = 1 ----
    spmm_csr<<<ug, 256, 0, stream>>>(uptr, uedge, bufA, ybuf, NUSERS);
    spmm2_first<<<ig, 256, 0, stream>>>(iptr, iedge, ybuf, bufA, bufB, obuf,
                                        c[0], c[1], NITEMS);

    float* t0 = bufA;
    float* t1 = bufB;
    for (int k = 2; k <= ORDER; ++k) {
        spmm_csr<<<ug, 256, 0, stream>>>(uptr, uedge, t1, ybuf, NUSERS);
        spmm2_k<<<ig, 256, 0, stream>>>(iptr, iedge, ybuf, t1, t0, obuf,
                                        c[k], NITEMS);
        float* tmp = t0; t0 = t1; t1 = tmp;
    }

    // ---- d_out = obuf^T ----
    transpose_k<<<dim3((BATCH + 31) / 32, (NITEMS + 31) / 32), tb, 0, stream>>>(
        obuf, (float*)d_out, NITEMS, BATCH);
}

// Round 5
// 1507.507 us; speedup vs baseline: 1.3595x; 1.3595x over previous
//
#include <hip/hip_runtime.h>
#include <math.h>

#define NUSERS 100000
#define NITEMS 50000
#define BATCH  64
#define ORDER  8
#define SCAN_BLOCKS 256

// Packed edge: gather index + value, one 8B unit
struct __align__(8) Edge { int idx; float val; };

// ---------------------------------------------------------------------------
// 32x32 LDS-tiled transpose: in[R][C] -> out[C][R]
// ---------------------------------------------------------------------------
__global__ void transpose_k(const float* __restrict__ in, float* __restrict__ out,
                            int R, int C) {
    __shared__ float tile[32][33];
    const int cb = blockIdx.x * 32;
    const int rb = blockIdx.y * 32;
    for (int i = threadIdx.y; i < 32; i += 8) {
        int r = rb + i, c = cb + threadIdx.x;
        if (r < R && c < C) tile[i][threadIdx.x] = in[(size_t)r * C + c];
    }
    __syncthreads();
    for (int i = threadIdx.y; i < 32; i += 8) {
        int c = cb + i, r = rb + threadIdx.x;
        if (c < C && r < R) out[(size_t)c * R + r] = tile[threadIdx.x][i];
    }
}

// ---------------------------------------------------------------------------
// CSR construction
// ---------------------------------------------------------------------------
__global__ void hist_k(const int* __restrict__ row, const int* __restrict__ col,
                       int* __restrict__ udeg, int* __restrict__ ideg, int nnz) {
    int i = blockIdx.x * blockDim.x + threadIdx.x;
    if (i < nnz) {
        atomicAdd(&udeg[row[i]], 1);
        atomicAdd(&ideg[col[i]], 1);
    }
}

__global__ void scan_partial(const int* __restrict__ deg, int* __restrict__ bsum, int n) {
    __shared__ int ls[256];
    const int chunk = (n + SCAN_BLOCKS - 1) / SCAN_BLOCKS;
    const int b0 = blockIdx.x * chunk;
    const int e0 = min(b0 + chunk, n);
    int s = 0;
    for (int i = b0 + threadIdx.x; i < e0; i += 256) s += deg[i];
    ls[threadIdx.x] = s;
    __syncthreads();
    for (int off = 128; off > 0; off >>= 1) {
        if (threadIdx.x < off) ls[threadIdx.x] += ls[threadIdx.x + off];
        __syncthreads();
    }
    if (threadIdx.x == 0) bsum[blockIdx.x] = ls[0];
}

__global__ void scan_bsum(const int* __restrict__ bsum, int* __restrict__ bofs) {
    __shared__ int ls[SCAN_BLOCKS];
    const int t = threadIdx.x;
    int v = bsum[t];
    ls[t] = v;
    __syncthreads();
    for (int off = 1; off < SCAN_BLOCKS; off <<= 1) {
        int u = (t >= off) ? ls[t - off] : 0;
        __syncthreads();
        ls[t] += u;
        __syncthreads();
    }
    bofs[t] = ls[t] - v;
}

__global__ void scan_final(const int* __restrict__ deg, const int* __restrict__ bofs,
                           int* __restrict__ ptr, int* __restrict__ cur, int n) {
    __shared__ int ls[256];
    const int chunk = (n + SCAN_BLOCKS - 1) / SCAN_BLOCKS;
    const int b0 = blockIdx.x * chunk;
    const int e0 = min(b0 + chunk, n);
    int carry = bofs[blockIdx.x];
    for (int base = b0; base < e0; base += 256) {
        int i = base + threadIdx.x;
        int v = (i < e0) ? deg[i] : 0;
        ls[threadIdx.x] = v;
        __syncthreads();
        for (int off = 1; off < 256; off <<= 1) {
            int u = (threadIdx.x >= off) ? ls[threadIdx.x - off] : 0;
            __syncthreads();
            ls[threadIdx.x] += u;
            __syncthreads();
        }
        if (i < e0) {
            int excl = carry + ls[threadIdx.x] - v;
            ptr[i] = excl;
            cur[i] = excl;
        }
        int tilesum = ls[255];
        __syncthreads();
        carry += tilesum;
    }
    if (blockIdx.x == SCAN_BLOCKS - 1 && threadIdx.x == 0)
        ptr[n] = carry;
}

// Direct scatter fill (round-3 variant: measured 290us; bucketed version
// regressed to 626us from atomic contention on few counters -- reverted).
__global__ void fill_k(const int* __restrict__ row, const int* __restrict__ col,
                       const float* __restrict__ vals,
                       int* __restrict__ ucur, Edge* __restrict__ uedge,
                       int* __restrict__ icur, Edge* __restrict__ iedge,
                       int nnz) {
    int i = blockIdx.x * blockDim.x + threadIdx.x;
    if (i < nnz) {
        int r = row[i], c = col[i];
        float v = vals[i];
        int p = atomicAdd(&ucur[r], 1);
        uedge[p] = Edge{c, v};
        int q = atomicAdd(&icur[c], 1);
        iedge[q] = Edge{r, v};
    }
}

// ---------------------------------------------------------------------------
// Gather SpMM, float4 layout: one wave per output row; lane = (edge_slot,
// batch_quad): sub = lane>>4 picks one of 4 concurrent edges, (lane&15)*4
// picks 4 batch elements. One wave VMEM instruction gathers 4 edges (1KB).
// Cross-slot reduction via shfl_xor(16), shfl_xor(32).
// ---------------------------------------------------------------------------
__device__ __forceinline__ float4 gather_row4(const int* __restrict__ ptr,
                                              const Edge* __restrict__ ed,
                                              const float* __restrict__ x,
                                              int r, int sub, int bq) {
    const int b = ptr[r], e = ptr[r + 1];
    float4 acc = {0.f, 0.f, 0.f, 0.f};
    for (int j = b + sub; j < e; j += 4) {
        Edge eo = ed[j];
        const float4 xv = *(const float4*)&x[(size_t)eo.idx * BATCH + bq];
        acc.x += eo.val * xv.x;
        acc.y += eo.val * xv.y;
        acc.z += eo.val * xv.z;
        acc.w += eo.val * xv.w;
    }
    // combine the 4 edge slots (lanes L, L^16, L^32, L^48)
    acc.x += __shfl_xor(acc.x, 16); acc.y += __shfl_xor(acc.y, 16);
    acc.z += __shfl_xor(acc.z, 16); acc.w += __shfl_xor(acc.w, 16);
    acc.x += __shfl_xor(acc.x, 32); acc.y += __shfl_xor(acc.y, 32);
    acc.z += __shfl_xor(acc.z, 32); acc.w += __shfl_xor(acc.w, 32);
    return acc;
}

__global__ void spmm_csr(const int* __restrict__ ptr, const Edge* __restrict__ ed,
                         const float* __restrict__ x, float* __restrict__ y, int nrows) {
    const int lane = threadIdx.x & 63;
    const int r = (blockIdx.x * blockDim.x + threadIdx.x) >> 6;
    if (r >= nrows) return;
    const int sub = lane >> 4;
    const int bq  = (lane & 15) << 2;
    float4 acc = gather_row4(ptr, ed, x, r, sub, bq);
    if (sub == 0) *(float4*)&y[(size_t)r * BATCH + bq] = acc;
}

// Second SpMM fused with first Chebyshev combine: t1 = s-2z; out = c0*s+c1*t1
__global__ void spmm2_first(const int* __restrict__ ptr, const Edge* __restrict__ ed,
                            const float* __restrict__ y, const float* __restrict__ s,
                            float* __restrict__ t1, float* __restrict__ out,
                            float c0, float c1, int nrows) {
    const int lane = threadIdx.x & 63;
    const int r = (blockIdx.x * blockDim.x + threadIdx.x) >> 6;
    if (r >= nrows) return;
    const int sub = lane >> 4;
    const int bq  = (lane & 15) << 2;
    float4 z = gather_row4(ptr, ed, y, r, sub, bq);
    if (sub == 0) {
        size_t base = (size_t)r * BATCH + bq;
        float4 sv = *(const float4*)&s[base];
        float4 t;
        t.x = sv.x - 2.0f * z.x; t.y = sv.y - 2.0f * z.y;
        t.z = sv.z - 2.0f * z.z; t.w = sv.w - 2.0f * z.w;
        *(float4*)&t1[base] = t;
        float4 o;
        o.x = c0 * sv.x + c1 * t.x; o.y = c0 * sv.y + c1 * t.y;
        o.z = c0 * sv.z + c1 * t.z; o.w = c0 * sv.w + c1 * t.w;
        *(float4*)&out[base] = o;
    }
}

// Second SpMM fused with general step: t2 = 2*t1-4*z-t0; out += ck*t2; t0 <- t2
__global__ void spmm2_k(const int* __restrict__ ptr, const Edge* __restrict__ ed,
                        const float* __restrict__ y, const float* __restrict__ t1,
                        float* __restrict__ t0t2, float* __restrict__ out,
                        float ck, int nrows) {
    const int lane = threadIdx.x & 63;
    const int r = (blockIdx.x * blockDim.x + threadIdx.x) >> 6;
    if (r >= nrows) return;
    const int sub = lane >> 4;
    const int bq  = (lane & 15) << 2;
    float4 z = gather_row4(ptr, ed, y, r, sub, bq);
    if (sub == 0) {
        size_t base = (size_t)r * BATCH + bq;
        float4 t1v = *(const float4*)&t1[base];
        float4 t0v = *(const float4*)&t0t2[base];
        float4 t2;
        t2.x = 2.0f * t1v.x - 4.0f * z.x - t0v.x;
        t2.y = 2.0f * t1v.y - 4.0f * z.y - t0v.y;
        t2.z = 2.0f * t1v.z - 4.0f * z.z - t0v.z;
        t2.w = 2.0f * t1v.w - 4.0f * z.w - t0v.w;
        *(float4*)&t0t2[base] = t2;
        float4 ov = *(const float4*)&out[base];
        ov.x += ck * t2.x; ov.y += ck * t2.y;
        ov.z += ck * t2.z; ov.w += ck * t2.w;
        *(float4*)&out[base] = ov;
    }
}

// ---------------------------------------------------------------------------
// Host-side exact replica of reference cheby_coeffs
// ---------------------------------------------------------------------------
static void cheby_coeffs_host(float* c) {
    const int order = ORDER, flatness = 2;
    const double PI = 3.14159265358979323846;
    double tgt[ORDER + 1], nodes[ORDER + 1];
    for (int x = 0; x <= order; ++x) {
        double xv = cos((double)(order - x) / order * PI);
        xv = nearbyint(xv * 1000.0) / 1000.0;
        double t = (xv < 0.0) ? pow(-xv, (double)flatness) * 0.5 + 0.5
                              : pow(xv, (double)flatness) * (-0.5) + 0.5;
        tgt[x] = nearbyint(t * 1000.0) / 1000.0;
    }
    for (int k = 1; k <= order + 1; ++k)
        nodes[k - 1] = cos((order + 1 + 0.5 - k) / (double)(order + 1) * PI);

    double prev[ORDER + 1], cur[ORDER + 1], nxt[ORDER + 1];
    double sums[ORDER + 1];
    double s0 = 0, s1 = 0;
    for (int i = 0; i <= order; ++i) {
        prev[i] = tgt[i];
        cur[i]  = nodes[i] * tgt[i];
        s0 += prev[i];
        s1 += cur[i];
    }
    sums[0] = s0; sums[1] = s1;
    for (int j = 2; j <= order; ++j) {
        double s = 0;
        for (int i = 0; i <= order; ++i) {
            nxt[i] = nodes[i] * cur[i] * 2.0 - prev[i];
            s += nxt[i];
        }
        sums[j] = s;
        for (int i = 0; i <= order; ++i) { prev[i] = cur[i]; cur[i] = nxt[i]; }
    }
    for (int j = 0; j <= order; ++j)
        c[j] = (float)(sums[j] * (2.0 / (order + 1)));
    c[0] *= 0.5f;
}

extern "C" void kernel_launch(void* const* d_in, const int* in_sizes, int n_in,
                              void* d_out, int out_size, void* d_ws, size_t ws_size,
                              hipStream_t stream) {
    const float* signal = (const float*)d_in[0];   // [BATCH, NITEMS]
    const float* vals   = (const float*)d_in[1];   // [NNZ]
    const int*   row    = (const int*)d_in[2];     // [NNZ] -> users
    const int*   col    = (const int*)d_in[3];     // [NNZ] -> items
    const int nnz = in_sizes[1];

    char* wsb = (char*)d_ws;
    size_t off = 0;
    auto carve = [&](size_t nbytes) {
        void* p = wsb + off;
        off += (nbytes + 255) & ~(size_t)255;   // 256B align -> float4 rows aligned
        return p;
    };
    const size_t NB = (size_t)NITEMS * BATCH;
    const size_t UB = (size_t)NUSERS * BATCH;
    float* bufA = (float*)carve(NB * 4);
    float* bufB = (float*)carve(NB * 4);
    float* obuf = (float*)carve(NB * 4);
    float* ybuf = (float*)carve(UB * 4);
    int*   udeg = (int*)carve(NUSERS * 4);
    int*   ideg = (int*)carve(NITEMS * 4);
    int*   uptr = (int*)carve((NUSERS + 1) * 4);
    int*   ucur = (int*)carve(NUSERS * 4);
    int*   iptr = (int*)carve((NITEMS + 1) * 4);
    int*   icur = (int*)carve(NITEMS * 4);
    int*   bsum = (int*)carve(SCAN_BLOCKS * 4);
    int*   bofs = (int*)carve(SCAN_BLOCKS * 4);
    Edge*  uedge = (Edge*)carve((size_t)nnz * 8);
    Edge*  iedge = (Edge*)carve((size_t)nnz * 8);
    (void)ws_size;

    float c[ORDER + 1];
    cheby_coeffs_host(c);

    // ---- CSR build ----
    hipMemsetAsync(udeg, 0, NUSERS * 4, stream);
    hipMemsetAsync(ideg, 0, NITEMS * 4, stream);
    hist_k<<<(nnz + 255) / 256, 256, 0, stream>>>(row, col, udeg, ideg, nnz);

    scan_partial<<<SCAN_BLOCKS, 256, 0, stream>>>(udeg, bsum, NUSERS);
    scan_bsum<<<1, SCAN_BLOCKS, 0, stream>>>(bsum, bofs);
    scan_final<<<SCAN_BLOCKS, 256, 0, stream>>>(udeg, bofs, uptr, ucur, NUSERS);

    scan_partial<<<SCAN_BLOCKS, 256, 0, stream>>>(ideg, bsum, NITEMS);
    scan_bsum<<<1, SCAN_BLOCKS, 0, stream>>>(bsum, bofs);
    scan_final<<<SCAN_BLOCKS, 256, 0, stream>>>(ideg, bofs, iptr, icur, NITEMS);

    fill_k<<<(nnz + 255) / 256, 256, 0, stream>>>(row, col, vals,
                                                  ucur, uedge, icur, iedge, nnz);

    // ---- s = signal^T ----
    dim3 tb(32, 8);
    transpose_k<<<dim3((NITEMS + 31) / 32, (BATCH + 31) / 32), tb, 0, stream>>>(
        signal, bufA, BATCH, NITEMS);

    const int ug = (NUSERS * 64 + 255) / 256;
    const int ig = (NITEMS * 64 + 255) / 256;

    // ---- k = 1 ----
    spmm_csr<<<ug, 256, 0, stream>>>(uptr, uedge, bufA, ybuf, NUSERS);
    spmm2_first<<<ig, 256, 0, stream>>>(iptr, iedge, ybuf, bufA, bufB, obuf,
                                        c[0], c[1], NITEMS);

    float* t0 = bufA;
    float* t1 = bufB;
    for (int k = 2; k <= ORDER; ++k) {
        spmm_csr<<<ug, 256, 0, stream>>>(uptr, uedge, t1, ybuf, NUSERS);
        spmm2_k<<<ig, 256, 0, stream>>>(iptr, iedge, ybuf, t1, t0, obuf,
                                        c[k], NITEMS);
        float* tmp = t0; t0 = t1; t1 = tmp;
    }

    // ---- d_out = obuf^T ----
    transpose_k<<<dim3((BATCH + 31) / 32, (NITEMS + 31) / 32), tb, 0, stream>>>(
        obuf, (float*)d_out, NITEMS, BATCH);
}